// Round 11
// baseline (24341.411 us; speedup 1.0000x reference)
//
#include <hip/hip_runtime.h>

typedef unsigned short u16;
typedef unsigned int u32;
typedef __attribute__((ext_vector_type(4))) float f32x4;
typedef __attribute__((ext_vector_type(4))) short s16x4;
typedef __attribute__((ext_vector_type(8))) short short8;

#define TB 512
#define NB 32
#define HID 512
#define LAT 128

__device__ __forceinline__ u16 f2bf(float f){ union{float f; u32 i;} x; x.f = f; u32 u = x.i; return (u16)((u + 0x7FFFu + ((u>>16)&1u))>>16); }
__device__ __forceinline__ float bf2f(u16 v){ union{u32 i; float f;} x; x.i = ((u32)v)<<16; return x.f; }
__device__ __forceinline__ float sigm(float x){ return 1.f/(1.f+expf(-x)); }
__device__ __forceinline__ float sofp(float x){ return x>20.f ? x : log1pf(expf(x)); }

__device__ __forceinline__ f32x4 mfma16(short8 a, short8 b, f32x4 c){
  return __builtin_amdgcn_mfma_f32_16x16x32_bf16(a, b, c, 0, 0, 0);
}

// pack 8 consecutive f32 -> short8 of bf16 (RNE)
__device__ __forceinline__ short8 pack8(const float* p){
  f32x4 a = *(const f32x4*)p;
  f32x4 b = *(const f32x4*)(p+4);
  short8 r;
  r[0]=(short)f2bf(a[0]); r[1]=(short)f2bf(a[1]); r[2]=(short)f2bf(a[2]); r[3]=(short)f2bf(a[3]);
  r[4]=(short)f2bf(b[0]); r[5]=(short)f2bf(b[1]); r[6]=(short)f2bf(b[2]); r[7]=(short)f2bf(b[3]);
  return r;
}
__device__ __forceinline__ s16x4 pack4(f32x4 v){
  s16x4 r;
  r[0]=(short)f2bf(v[0]); r[1]=(short)f2bf(v[1]); r[2]=(short)f2bf(v[2]); r[3]=(short)f2bf(v[3]);
  return r;
}

// ---- device-scope grid barrier (64 blocks, all co-resident on 256 CUs) ----
__device__ __forceinline__ void gridbar(u32* bar, u32 nblk){
  __syncthreads();
  if (threadIdx.x == 0){
    __threadfence();
    u32 g = __hip_atomic_load(bar+16, __ATOMIC_RELAXED, __HIP_MEMORY_SCOPE_AGENT);
    u32 a = __hip_atomic_fetch_add(bar, 1u, __ATOMIC_ACQ_REL, __HIP_MEMORY_SCOPE_AGENT);
    if (a == nblk-1u){
      __hip_atomic_store(bar, 0u, __ATOMIC_RELAXED, __HIP_MEMORY_SCOPE_AGENT);
      __hip_atomic_fetch_add(bar+16, 1u, __ATOMIC_RELEASE, __HIP_MEMORY_SCOPE_AGENT);
    } else {
      while (__hip_atomic_load(bar+16, __ATOMIC_ACQUIRE, __HIP_MEMORY_SCOPE_AGENT) == g)
        __builtin_amdgcn_s_sleep(1);
    }
    __threadfence();
  }
  __syncthreads();
}

// =============================== LSTM chunk ===============================
// f32 I/O; bf16 staged into LDS + W fragments in registers for MFMA.
// 64 blocks x 256 thr; block owns 8 hidden units (32 gate cols i,f,g,o x 8).
// Two-phase K loop reuses ONE 32KB LDS tile. Static LDS = 48.2 KB.
template<int DIN>
__launch_bounds__(256, 1)
__global__ void lstm_chunk(const float* __restrict__ xin,
                           const float* __restrict__ Wih, const float* __restrict__ Whh,
                           const float* __restrict__ bih, const float* __restrict__ bhh,
                           float* __restrict__ houtc, float* __restrict__ hstate,
                           float* __restrict__ cstate, u32* bar,
                           const int t0, const int C)
{
  __shared__ char  sHX[32768];   // [32 rows][1024B] bf16 swizzled (phase-shared)
  __shared__ float sgp[4096];    // [4 waves][32][32] partials
  __shared__ float sbs[32];      // bih+bhh

  const int tid = threadIdx.x, lane = tid & 63, wv = tid >> 6;
  const int u0 = blockIdx.x * 8;
  const int l15 = lane & 15, hi = lane >> 4;
  constexpr int NX = (DIN == 512) ? 4 : 1;

  // preload W fragments (B-frag: col=lane&15, k=hi*8+j), f32 -> bf16
  short8 wreg[2][4 + NX];
  #pragma unroll
  for (int c = 0; c < 2; ++c){
    const int col = c*16 + l15;
    const int grow = ((col>>3)<<9) + u0 + (col&7);
    #pragma unroll
    for (int i = 0; i < 4; ++i){
      const int k = (wv*4 + i)*32 + hi*8;
      wreg[c][i] = pack8(Whh + (size_t)grow*512 + k);
    }
    #pragma unroll
    for (int j = 0; j < NX; ++j){
      short8 v;
      if (DIN == 512){
        v = pack8(Wih + (size_t)grow*512 + (wv*4 + j)*32 + hi*8);
      } else if (wv < 2){
        v = pack8(Wih + (size_t)grow*64 + wv*32 + hi*8);
      } else {
        #pragma unroll
        for (int q=0;q<8;++q) v[q] = 0;
      }
      wreg[c][4+j] = v;
    }
  }
  if (tid < 32){
    int grow = ((tid>>3)<<9) + u0 + (tid&7);
    sbs[tid] = bih[grow] + bhh[grow];
  }
  const int eb = tid >> 3, eu = tid & 7;
  float cst = cstate[eb*HID + u0 + eu];
  const int r0 = l15, r1 = 16 + l15;
  const int swz = l15 << 4;

  for (int trel = 0; trel < C; ++trel){
    const int t = t0 + trel;
    // ---- phase A: stage h_{t-1} (f32 -> bf16) ----
    {
      const float* hsrc = (trel == 0) ? hstate : (houtc + (size_t)(trel-1)*(NB*HID));
      for (int s = tid; s < 4096; s += 256){     // 32 rows x 128 float4-chunks
        int row = s >> 7, q = s & 127;
        f32x4 v = *(const f32x4*)(hsrc + (size_t)row*HID + q*4);
        int byte = ((((q>>1)<<4) ^ ((row&15)<<4)) + ((q&1)<<3));
        *(s16x4*)(sHX + (row<<10) + byte) = pack4(v);
      }
    }
    __syncthreads();
    f32x4 a00={0.f,0.f,0.f,0.f}, a01={0.f,0.f,0.f,0.f};
    f32x4 a10={0.f,0.f,0.f,0.f}, a11={0.f,0.f,0.f,0.f};
    #pragma unroll
    for (int i = 0; i < 4; ++i){
      const int o = (((wv*4 + i)<<6) + (hi<<4)) ^ swz;
      short8 x0 = *(const short8*)(sHX + (r0<<10) + o);
      short8 x1 = *(const short8*)(sHX + (r1<<10) + o);
      a00 = mfma16(x0, wreg[0][i], a00);
      a01 = mfma16(x0, wreg[1][i], a01);
      a10 = mfma16(x1, wreg[0][i], a10);
      a11 = mfma16(x1, wreg[1][i], a11);
    }
    __syncthreads();            // all reads done before restaging
    // ---- phase B: stage x_t into the same tile ----
    if (DIN == 512){
      const float* xsrc = xin + (size_t)trel*(NB*512);
      for (int s = tid; s < 4096; s += 256){
        int row = s >> 7, q = s & 127;
        f32x4 v = *(const f32x4*)(xsrc + (size_t)row*512 + q*4);
        int byte = ((((q>>1)<<4) ^ ((row&15)<<4)) + ((q&1)<<3));
        *(s16x4*)(sHX + (row<<10) + byte) = pack4(v);
      }
    } else {
      for (int s = tid; s < 512; s += 256){      // 32 rows x 16 chunks
        int row = s >> 4, q = s & 15;
        f32x4 v = *(const f32x4*)(xin + ((size_t)row*TB + t)*64 + q*4);
        int byte = ((((q>>1)<<4) ^ ((row&15)<<4)) + ((q&1)<<3));
        *(s16x4*)(sHX + (row<<10) + byte) = pack4(v);
      }
    }
    __syncthreads();
    if (DIN == 512){
      #pragma unroll
      for (int j = 0; j < 4; ++j){
        const int o = (((wv*4 + j)<<6) + (hi<<4)) ^ swz;
        short8 x0 = *(const short8*)(sHX + (r0<<10) + o);
        short8 x1 = *(const short8*)(sHX + (r1<<10) + o);
        a00 = mfma16(x0, wreg[0][4+j], a00);
        a01 = mfma16(x0, wreg[1][4+j], a01);
        a10 = mfma16(x1, wreg[0][4+j], a10);
        a11 = mfma16(x1, wreg[1][4+j], a11);
      }
    } else if (wv < 2){
      const int o = ((wv<<6) + (hi<<4)) ^ swz;
      short8 x0 = *(const short8*)(sHX + (r0<<10) + o);
      short8 x1 = *(const short8*)(sHX + (r1<<10) + o);
      a00 = mfma16(x0, wreg[0][4], a00);
      a01 = mfma16(x0, wreg[1][4], a01);
      a10 = mfma16(x1, wreg[0][4], a10);
      a11 = mfma16(x1, wreg[1][4], a11);
    }
    // ---- wave partials to LDS ----
    {
      float* g = sgp + (wv<<10);
      const int rr = hi << 2;
      #pragma unroll
      for (int r = 0; r < 4; ++r){
        g[((rr+r)<<5)    + l15]      = a00[r];
        g[((rr+r)<<5)    + 16 + l15] = a01[r];
        g[((rr+r+16)<<5) + l15]      = a10[r];
        g[((rr+r+16)<<5) + 16 + l15] = a11[r];
      }
    }
    __syncthreads();
    // ---- epilogue: thread (b=eb, unit=eu) ----
    {
      int base = (eb<<5) + eu;
      float vi = sbs[eu]    + sgp[base]    + sgp[1024+base]    + sgp[2048+base]    + sgp[3072+base];
      float vf = sbs[8+eu]  + sgp[base+8]  + sgp[1024+base+8]  + sgp[2048+base+8]  + sgp[3072+base+8];
      float vg = sbs[16+eu] + sgp[base+16] + sgp[1024+base+16] + sgp[2048+base+16] + sgp[3072+base+16];
      float vo = sbs[24+eu] + sgp[base+24] + sgp[1024+base+24] + sgp[2048+base+24] + sgp[3072+base+24];
      cst = sigm(vf)*cst + sigm(vi)*tanhf(vg);
      float h = sigm(vo)*tanhf(cst);
      houtc[((size_t)trel*NB + eb)*HID + u0 + eu] = h;
      if (trel == C-1) hstate[eb*HID + u0 + eu] = h;
    }
    if (trel + 1 < C) gridbar(bar, gridDim.x);
  }
  cstate[eb*HID + u0 + eu] = cst;
}

// =============================== GRU chunk ===============================
// 32 blocks x 128 thr; block = one batch; Whh in registers (bf16-packed,
// 192 VGPR); f32 math; h + KL state carried in global f32.
__launch_bounds__(128, 1)
__global__ void gru_chunk(const float* __restrict__ zgc, const float* __restrict__ Whh,
                          const float* __restrict__ bhh, const float* __restrict__ muc,
                          const float* __restrict__ lvc, float* __restrict__ gruh,
                          float* __restrict__ kaccg, const int C)
{
  __shared__ float hl[128];
  __shared__ float bh[384];
  const int tid = threadIdx.x;
  const int b = blockIdx.x;

  short8 wr[16], wu[16], wn[16];
  #pragma unroll
  for (int kc = 0; kc < 16; ++kc){
    wr[kc] = pack8(Whh + (size_t)(      tid)*128 + kc*8);
    wu[kc] = pack8(Whh + (size_t)(128 + tid)*128 + kc*8);
    wn[kc] = pack8(Whh + (size_t)(256 + tid)*128 + kc*8);
  }
  for (int s = tid; s < 384; s += 128) bh[s] = bhh[s];
  hl[tid] = gruh[b*128 + tid];
  float kacc = kaccg[b*128 + tid];
  __syncthreads();

  for (int trel = 0; trel < C; ++trel){
    const float* zr = zgc + ((size_t)trel*NB + b)*384;
    float xr = zr[tid];
    float xu = zr[128+tid];
    float xn = zr[256+tid];
    float hr0=0.f,hr1=0.f,hu0=0.f,hu1=0.f,hn0=0.f,hn1=0.f;
    #pragma unroll
    for (int kc = 0; kc < 16; ++kc){
      #pragma unroll
      for (int j = 0; j < 8; j += 2){
        float h0 = hl[kc*8+j], h1 = hl[kc*8+j+1];
        hr0 += h0*bf2f((u16)wr[kc][j]);  hr1 += h1*bf2f((u16)wr[kc][j+1]);
        hu0 += h0*bf2f((u16)wu[kc][j]);  hu1 += h1*bf2f((u16)wu[kc][j+1]);
        hn0 += h0*bf2f((u16)wn[kc][j]);  hn1 += h1*bf2f((u16)wn[kc][j+1]);
      }
    }
    float r  = sigm(xr + hr0+hr1 + bh[tid]);
    float uu = sigm(xu + hu0+hu1 + bh[128+tid]);
    float n  = tanhf(xn + r*(hn0+hn1 + bh[256+tid]));
    float hnew = (1.f-uu)*n + uu*hl[tid];
    const size_t mi = ((size_t)trel*NB + b)*LAT + tid;
    float m = muc[mi];
    float l = lvc[mi];
    float d = m - hnew;
    kacc += -0.5f*l + 0.5f*(expf(l) + d*d) - 0.5f;
    __syncthreads();
    hl[tid] = hnew;
    __syncthreads();
  }
  gruh[b*128 + tid] = hl[tid];
  kaccg[b*128 + tid] = kacc;
}

// ====================== generic NT GEMM: out = act(A@W^T + b) ======================
// A[M,K], W[N,K] f32 K-major; staged to bf16 LDS; f32 out. 64x64 tile, BK=64.
template<int K, int ACT>
__launch_bounds__(256, 2)
__global__ void gemm_nt(const float* __restrict__ A, const float* __restrict__ W,
                        const float* __restrict__ bias, float* __restrict__ out,
                        const int N)
{
  __shared__ char As[8192], Ws[8192];
  const int tid = threadIdx.x, lane = tid & 63, wv = tid >> 6;
  const int bm = blockIdx.x, bn = blockIdx.y;
  f32x4 acc0 = {0.f,0.f,0.f,0.f}, acc1 = {0.f,0.f,0.f,0.f};
  f32x4 acc2 = {0.f,0.f,0.f,0.f}, acc3 = {0.f,0.f,0.f,0.f};
  const int l15 = lane & 15;
  const int kg = (lane>>4)<<4;
  for (int kb = 0; kb < K; kb += 64){
    for (int s = tid; s < 2048; s += 256){     // {A,W} x 64 rows x 16 chunks
      int m = s >> 10, row = (s>>4)&63, q = s&15;
      const float* src = m ? (W + (size_t)(bn*64+row)*K + kb + q*4)
                           : (A + (size_t)(bm*64+row)*K + kb + q*4);
      f32x4 v = *(const f32x4*)src;
      int byte = ((((q>>1)<<4) ^ ((row&7)<<4)) + ((q&1)<<3));
      *(s16x4*)((m ? Ws : As) + row*128 + byte) = pack4(v);
    }
    __syncthreads();
    #pragma unroll
    for (int kk = 0; kk < 2; ++kk){
      int arow = wv*16 + l15;
      short8 a  = *(const short8*)(As + arow*128     + (((kk<<6) + kg) ^ ((arow&7)<<4)));
      short8 b0 = *(const short8*)(Ws + (l15)*128    + (((kk<<6) + kg) ^ ((l15&7)<<4)));
      short8 b1 = *(const short8*)(Ws + (16+l15)*128 + (((kk<<6) + kg) ^ ((l15&7)<<4)));
      short8 b2 = *(const short8*)(Ws + (32+l15)*128 + (((kk<<6) + kg) ^ ((l15&7)<<4)));
      short8 b3 = *(const short8*)(Ws + (48+l15)*128 + (((kk<<6) + kg) ^ ((l15&7)<<4)));
      acc0 = mfma16(a, b0, acc0);
      acc1 = mfma16(a, b1, acc1);
      acc2 = mfma16(a, b2, acc2);
      acc3 = mfma16(a, b3, acc3);
    }
    __syncthreads();
  }
  #pragma unroll
  for (int nf = 0; nf < 4; ++nf){
    f32x4 acc = (nf==0) ? acc0 : (nf==1) ? acc1 : (nf==2) ? acc2 : acc3;
    int gcol = bn*64 + nf*16 + l15;
    float bv = bias[gcol];
    #pragma unroll
    for (int r = 0; r < 4; ++r){
      int grow = bm*64 + wv*16 + ((lane>>4)<<2) + r;
      float v = acc[r] + bv;
      if (ACT) v = v * sigm(v);
      out[(size_t)grow*N + gcol] = v;
    }
  }
}

// ---- z = mu + exp(0.5 lv)*eps -> zc [trel][b][128] (ws) AND d_out [b][t][128] ----
__global__ void rsample_chunk(const float* __restrict__ muc, const float* __restrict__ lvc,
                              const float* __restrict__ eps, float* __restrict__ zc,
                              float* __restrict__ zout, const int t0)
{
  int idx = blockIdx.x*256 + threadIdx.x;     // 4096*C total, grid exact
  int r = idx >> 7, l = idx & 127;
  int trel = r >> 5, b = r & 31;
  float m = muc[idx];
  float s = expf(0.5f*lvc[idx]);
  size_t gi = ((size_t)(b<<9) + t0 + trel)*LAT + l;
  float z = m + s*eps[gi];
  zc[idx] = z;
  zout[gi] = z;
}

// ---- LayerNorm(hd + r2)*g + b, in-place over hd (block owns its row) ----
__launch_bounds__(256)
__global__ void ln_chunk(const float* __restrict__ hd, const float* __restrict__ r2,
                         const float* __restrict__ g, const float* __restrict__ bb,
                         float* __restrict__ out)
{
  __shared__ float ss[4], qq[4];
  const int row = blockIdx.x, tid = threadIdx.x;
  const float* h0 = hd + (size_t)row*512;
  const float* r0 = r2 + (size_t)row*512;
  float x0 = h0[tid] + r0[tid];
  float x1 = h0[256+tid] + r0[256+tid];
  float s = x0 + x1, q = x0*x0 + x1*x1;
  #pragma unroll
  for (int o = 32; o; o >>= 1){ s += __shfl_down(s, o, 64); q += __shfl_down(q, o, 64); }
  if ((tid&63) == 0){ ss[tid>>6] = s; qq[tid>>6] = q; }
  __syncthreads();
  s = ss[0]+ss[1]+ss[2]+ss[3];
  q = qq[0]+qq[1]+qq[2]+qq[3];
  float mean = s*(1.f/512.f);
  float var = q*(1.f/512.f) - mean*mean;
  if (var < 0.f) var = 0.f;
  float inv = rsqrtf(var + 1e-5f);
  out[(size_t)row*512+tid]     = (x0-mean)*inv*g[tid]     + bb[tid];
  out[(size_t)row*512+256+tid] = (x1-mean)*inv*g[256+tid] + bb[256+tid];
}

// ---- student-t recon partials: rpart[bi] += chunk partial ----
__launch_bounds__(256)
__global__ void loss_chunk(const float* __restrict__ x, const float* __restrict__ dpc,
                           float* __restrict__ rpart, const int t0, const int nelem)
{
  __shared__ float red[256];
  float acc = 0.f;
  for (int idx = blockIdx.x*256 + threadIdx.x; idx < nelem; idx += 256*256){
    int r = idx >> 6, d = idx & 63;
    int trel = r >> 5, b = r & 31;
    float xv = x[((size_t)(b<<9) + t0 + trel)*64 + d];
    float m  = dpc[(size_t)r*192 + d];
    float sc = sofp(dpc[(size_t)r*192 + 64 + d]) + 1e-4f;
    float df = sofp(dpc[(size_t)r*192 + 128 + d]) + 2.f;
    float tt = (xv - m)/sc;
    float lp = lgammaf(0.5f*(df+1.f)) - lgammaf(0.5f*df)
             - 0.5f*logf(df*3.14159265358979f)
             - logf(sc)
             - 0.5f*(df+1.f)*log1pf(tt*tt/df);
    acc -= lp;
  }
  red[threadIdx.x] = acc; __syncthreads();
  for (int o = 128; o; o >>= 1){ if (threadIdx.x < o) red[threadIdx.x] += red[threadIdx.x+o]; __syncthreads(); }
  if (threadIdx.x == 0) rpart[blockIdx.x] += red[0];
}

// ---- NaN/Inf stage scan: sets bit in flags if buffer is bad ----
__global__ void scan_k(const float* __restrict__ p, long n, int bit, u32* flags)
{
  u32 bad = 0;
  for (long i = blockIdx.x*256 + threadIdx.x; i < n; i += (long)gridDim.x*256){
    float v = p[i];
    if (!(fabsf(v) <= 1e30f)) bad = 1;      // catches NaN and huge/Inf
  }
  if (bad) atomicOr(flags, 1u << bit);
}

__launch_bounds__(512)
__global__ void final_k(const float* __restrict__ rpart, const float* __restrict__ kaccg,
                        const u32* __restrict__ flags, float* __restrict__ out)
{
  __shared__ float red[512];
  int tid = threadIdx.x;
  float v = (tid < 256) ? rpart[tid] : 0.f;
  #pragma unroll
  for (int j = 0; j < 8; ++j) v += kaccg[tid*8 + j];
  red[tid] = v; __syncthreads();
  for (int o = 256; o; o >>= 1){ if (tid < o) red[tid] += red[tid+o]; __syncthreads(); }
  if (tid == 0){
    u32 f = *flags;
    if (f) out[0] = ldexpf(1.f, 21 + (__ffs(f) - 1));   // diagnostic code
    else   out[0] = red[0]*(1.f/32.f);
  }
}

extern "C" void kernel_launch(void* const* d_in, const int* in_sizes, int n_in,
                              void* d_out, int out_size, void* d_ws, size_t ws_size,
                              hipStream_t stream)
{
  (void)in_sizes; (void)n_in; (void)out_size;
  const float* x    = (const float*)d_in[0];
  const float* eps  = (const float*)d_in[1];
  const float* Wih0 = (const float*)d_in[2];
  const float* Whh0 = (const float*)d_in[3];
  const float* bih0 = (const float*)d_in[4];
  const float* bhh0 = (const float*)d_in[5];
  const float* Wih1 = (const float*)d_in[6];
  const float* Whh1 = (const float*)d_in[7];
  const float* bih1 = (const float*)d_in[8];
  const float* bhh1 = (const float*)d_in[9];
  const float* Wih2 = (const float*)d_in[10];
  const float* Whh2 = (const float*)d_in[11];
  const float* bih2 = (const float*)d_in[12];
  const float* bhh2 = (const float*)d_in[13];
  const float* muW  = (const float*)d_in[14];
  const float* mub  = (const float*)d_in[15];
  const float* lvW  = (const float*)d_in[16];
  const float* lvb  = (const float*)d_in[17];
  const float* gWih = (const float*)d_in[18];
  const float* gWhh = (const float*)d_in[19];
  const float* gbih = (const float*)d_in[20];
  const float* gbhh = (const float*)d_in[21];
  const float* dW1  = (const float*)d_in[22];
  const float* db1  = (const float*)d_in[23];
  const float* rW1  = (const float*)d_in[24];
  const float* rb1  = (const float*)d_in[25];
  const float* rW2  = (const float*)d_in[26];
  const float* rb2  = (const float*)d_in[27];
  const float* lng  = (const float*)d_in[28];
  const float* lnb  = (const float*)d_in[29];
  const float* dW2  = (const float*)d_in[30];
  const float* db2  = (const float*)d_in[31];

  // ---- chunk size from real ws_size: fixed 512KB + 288KB*C (all f32) ----
  int C = 256;
  while (C > 2 && (size_t)524288 + (size_t)294912*(size_t)C > ws_size) C >>= 1;
  const int nch = TB / C;

  char* ws = (char*)d_ws;
  // fixed region [0, 512KB)
  u32*   bar   = (u32*)  (ws);                      // 256 B
  u32*   flags = (u32*)  (ws + 256);
  float* rpart = (float*)(ws + 4096);               // 256 f32
  float* kaccg = (float*)(ws + 8192);               // 32x128 f32
  float* gruh  = (float*)(ws + 24576);              // 32x128 f32
  float* hst0  = (float*)(ws + 40960);              // 32x512 f32 (64KB)
  float* hst1  = (float*)(ws + 40960 + 65536);
  float* hst2  = (float*)(ws + 40960 + 131072);
  float* cst0  = (float*)(ws + 237568);             // 32x512 f32 (64KB)
  float* cst1  = (float*)(ws + 237568 + 65536);
  float* cst2  = (float*)(ws + 237568 + 131072);
  // chunk region [512KB, 512KB + 288KB*C)
  const size_t KCB = (size_t)C * 1024;              // bytes per "KB*C" unit
  char* cb = ws + 524288;
  float* h0c = (float*)(cb);                        // 64KCB
  float* h1c = (float*)(cb + 64*KCB);               // 64KCB
  float* h2c = (float*)(cb + 128*KCB);              // 64KCB
  float* muc = (float*)(cb + 192*KCB);              // 16KCB
  float* lvc = (float*)(cb + 208*KCB);              // 16KCB
  float* zc  = (float*)(cb + 224*KCB);              // 16KCB
  float* zgc = (float*)(cb + 240*KCB);              // 48KCB
  float* dpc = muc;                                 // 24KCB overlay (mu/lv dead)
  float* r1c = h0c;
  float* hdc = h1c;
  float* r2c = h2c;
  float* zo  = (float*)d_out + 1;

  size_t zbytes = 524288 + 288*KCB;
  if (zbytes > ws_size) zbytes = ws_size;
  (void)hipMemsetAsync(d_ws, 0, zbytes, stream);

  for (int ch = 0; ch < nch; ++ch){
    const int t0 = ch*C;
    lstm_chunk<64> <<<64, 256, 0, stream>>>(x,   Wih0, Whh0, bih0, bhh0, h0c, hst0, cst0, bar, t0, C);
    lstm_chunk<512><<<64, 256, 0, stream>>>(h0c, Wih1, Whh1, bih1, bhh1, h1c, hst1, cst1, bar, t0, C);
    lstm_chunk<512><<<64, 256, 0, stream>>>(h1c, Wih2, Whh2, bih2, bhh2, h2c, hst2, cst2, bar, t0, C);
    gemm_nt<512,0><<<dim3(C/2, 2), 256, 0, stream>>>(h2c, muW, mub, muc, 128);
    gemm_nt<512,0><<<dim3(C/2, 2), 256, 0, stream>>>(h2c, lvW, lvb, lvc, 128);
    rsample_chunk<<<16*C, 256, 0, stream>>>(muc, lvc, eps, zc, zo, t0);
    gemm_nt<128,0><<<dim3(C/2, 6), 256, 0, stream>>>(zc, gWih, gbih, zgc, 384);
    gru_chunk<<<32, 128, 0, stream>>>(zgc, gWhh, gbhh, muc, lvc, gruh, kaccg, C);
    gemm_nt<128,1><<<dim3(C/2, 8), 256, 0, stream>>>(zc,  dW1, db1, hdc, 512);
    gemm_nt<512,1><<<dim3(C/2, 8), 256, 0, stream>>>(hdc, rW1, rb1, r1c, 512);
    gemm_nt<512,0><<<dim3(C/2, 8), 256, 0, stream>>>(r1c, rW2, rb2, r2c, 512);
    ln_chunk<<<32*C, 256, 0, stream>>>(hdc, r2c, lng, lnb, hdc);
    gemm_nt<512,0><<<dim3(C/2, 3), 256, 0, stream>>>(hdc, dW2, db2, dpc, 192);
    loss_chunk<<<256, 256, 0, stream>>>(x, dpc, rpart, t0, 2048*C);
  }
  // diagnostic NaN scans (encode first bad stage into out[0] if any)
  scan_k<<<64, 256, 0, stream>>>(hst2,  16384,           0, flags);
  scan_k<<<64, 256, 0, stream>>>(cst2,  16384,           1, flags);
  scan_k<<<64, 256, 0, stream>>>(zc,    (long)4096*C,    2, flags);
  scan_k<<<64, 256, 0, stream>>>(zgc,   (long)12288*C,   3, flags);
  scan_k<<<64, 256, 0, stream>>>(kaccg, 4096,            4, flags);
  scan_k<<<64, 256, 0, stream>>>(hdc,   (long)16384*C,   5, flags);
  scan_k<<<64, 256, 0, stream>>>(dpc,   (long)6144*C,    6, flags);
  scan_k<<<64, 256, 0, stream>>>(rpart, 256,             7, flags);
  final_k<<<1, 512, 0, stream>>>(rpart, kaccg, flags, (float*)d_out);
}